// Round 9
// baseline (544.866 us; speedup 1.0000x reference)
//
#include <hip/hip_runtime.h>
#include <math.h>

#define B 8
#define N 512
#define D 128
#define H 4
#define TOK (B*N)   // 4096

typedef __attribute__((ext_vector_type(8))) short bfrag;   // 8 bf16 (4 VGPRs)
typedef __attribute__((ext_vector_type(4))) float facc;    // 4 fp32 acc
typedef unsigned short u16;
typedef unsigned int u32;

__device__ __forceinline__ float lrelu(float x){ return x > 0.f ? x : 0.01f*x; }
__device__ __forceinline__ u16 f2bf(float f){
  u32 u = __float_as_uint(f);
  u += 0x7fffu + ((u >> 16) & 1u);     // RTNE
  return (u16)(u >> 16);
}
__device__ __forceinline__ u32 pk2(float a, float b){
  return (u32)f2bf(a) | ((u32)f2bf(b) << 16);
}
__device__ __forceinline__ bfrag pack8(float4 a0, float4 a1){
  union { uint4 u; bfrag b; } cv;
  cv.u = (uint4){ pk2(a0.x,a0.y), pk2(a0.z,a0.w), pk2(a1.x,a1.y), pk2(a1.z,a1.w) };
  return cv.b;
}

// ---------------- unified prep: adj transpose + all weight bf16-transposes ----
__global__ void prep_kernel(const int* __restrict__ adj, int* __restrict__ adjT,
    const float* s0, const float* s1_, const float* s2_, const float* s3,
    const float* s4, const float* s5, const float* s6, const float* s7,
    const float* s8,
    u16* d0, u16* d1, u16* d2, u16* d3, u16* d4, u16* d5, u16* d6, u16* d7, u16* d8)
{
  __shared__ float ftile[32][33];
  const int tid = threadIdx.x;
  const int tx = tid & 31, ty = tid >> 5;
  if (blockIdx.x < 128){
    int* it = (int*)&ftile[0][0];
    const int b = blockIdx.x >> 4, i0 = (blockIdx.x & 15)*32;
    for (int j0 = 0; j0 < N; j0 += 32){
      for (int r = ty; r < 32; r += 8)
        it[r*33 + tx] = adj[((size_t)b*N + i0 + r)*N + j0 + tx];
      __syncthreads();
      for (int r = ty; r < 32; r += 8)
        adjT[((size_t)b*N + j0 + r)*N + i0 + tx] = it[tx*33 + r];
      __syncthreads();
    }
  } else {
    const float* srcs[9] = {s0,s1_,s2_,s3,s4,s5,s6,s7,s8};
    u16* dsts[9] = {d0,d1,d2,d3,d4,d5,d6,d7,d8};
    const int Ks[9] = {32,128,128,256,128,256,128,128,512};
    const int Ns[9] = {128,128,256,128,256,128,128,128,128};
    const int zs[9] = {1,1,1,1,1,1,24,2,6};
    for (int job = (int)blockIdx.x - 128; job < 948; job += 384){
      int m = 0, base = 0;
      for (; m < 9; ++m){
        int cnt = (Ks[m]>>5)*(Ns[m]>>5)*zs[m];
        if (job < base + cnt) break;
        base += cnt;
      }
      const int rem = job - base;
      const int tn = Ns[m] >> 5;
      const int per = (Ks[m] >> 5)*tn;
      const int z = rem / per, t = rem % per;
      const int k0 = (t / tn)*32, n0 = (t % tn)*32;
      const float* src = srcs[m] + (size_t)z*Ks[m]*Ns[m];
      u16* dst = dsts[m] + (size_t)z*Ks[m]*Ns[m];
      __syncthreads();
      for (int r = ty; r < 32; r += 8)
        ftile[r][tx] = src[(size_t)(k0+r)*Ns[m] + n0 + tx];
      __syncthreads();
      for (int r = ty; r < 32; r += 8)
        dst[(size_t)(n0+r)*Ks[m] + k0 + tx] = f2bf(ftile[tx][r]);
    }
  }
}

// ======== direct-from-global MFMA GEMMs (no LDS tiles, no K-loop barriers) ====
// Block 256 = 4 waves: wave w owns rows r0=(w&1)*16, cols c0=(w>>1)*64 (4 frags)
// A frag: lane(quad,l15) = A[r0+l15][k0+quad*8 ..+7]; B frag = BT[c][k0+quad*8..]
// C: col=l15 (within frag g), row=quad*4+reg.

// ---------------- generic GEMM, fp32 A (FEL stages) ---------------------------
// ACT: 0 none, 1 lrelu(x+bias). FIN 0: plain store; FIN 1: +res then LN.
template<int ACT, int FIN>
__global__ __launch_bounds__(256) void gemm32(
    const float* __restrict__ A, int lda, int K,
    const u16* __restrict__ BT, const float* __restrict__ bias,
    const float* __restrict__ res, float* __restrict__ out, int ldo)
{
  const int tid = threadIdx.x;
  const int t0 = blockIdx.x * 32;
  const int n0 = blockIdx.y * 128;
  __shared__ float scrS[4][16], scrQ[4][16];
  const int wave = tid >> 6, lane = tid & 63, quad = lane >> 4, l15 = lane & 15;
  const int r0 = (wave & 1)*16, c0 = (wave >> 1)*64;
  facc acc[4];
  #pragma unroll
  for (int g = 0; g < 4; ++g) acc[g] = (facc){0.f,0.f,0.f,0.f};
  const float* arow = A + (size_t)(t0 + r0 + l15)*lda + quad*8;
  const u16* Bg[4];
  #pragma unroll
  for (int g = 0; g < 4; ++g)
    Bg[g] = BT + (size_t)(n0 + c0 + g*16 + l15)*K + quad*8;

  for (int k0 = 0; k0 < K; k0 += 32){
    float4 a0 = *(const float4*)(arow + k0);
    float4 a1 = *(const float4*)(arow + k0 + 4);
    bfrag af = pack8(a0, a1);
    #pragma unroll
    for (int g = 0; g < 4; ++g){
      bfrag bf = *(const bfrag*)(Bg[g] + k0);
      acc[g] = __builtin_amdgcn_mfma_f32_16x16x32_bf16(af, bf, acc[g], 0,0,0);
    }
  }

  float bv[4];
  #pragma unroll
  for (int g = 0; g < 4; ++g) bv[g] = bias[n0 + c0 + g*16 + l15];

  if (FIN == 0){
    #pragma unroll
    for (int g = 0; g < 4; ++g){
      const int c = n0 + c0 + g*16 + l15;
      #pragma unroll
      for (int q = 0; q < 4; ++q){
        const int rq = t0 + r0 + quad*4 + q;
        float xv = acc[g][q] + bv[g];
        if (ACT) xv = lrelu(xv);
        out[(size_t)rq*ldo + c] = xv;
      }
    }
  } else {
    float v[4][4], s[4] = {0,0,0,0}, sq[4] = {0,0,0,0};
    #pragma unroll
    for (int g = 0; g < 4; ++g){
      const int c = c0 + g*16 + l15;
      #pragma unroll
      for (int q = 0; q < 4; ++q){
        const int rq = t0 + r0 + quad*4 + q;
        float xv = acc[g][q] + bv[g];
        if (ACT) xv = lrelu(xv);
        xv += res[(size_t)rq*128 + c];
        v[g][q] = xv; s[q] += xv; sq[q] += xv*xv;
      }
    }
    #pragma unroll
    for (int m = 1; m < 16; m <<= 1){
      #pragma unroll
      for (int q = 0; q < 4; ++q){ s[q] += __shfl_xor(s[q], m, 64); sq[q] += __shfl_xor(sq[q], m, 64); }
    }
    if (l15 == 0){
      #pragma unroll
      for (int q = 0; q < 4; ++q){ scrS[wave][quad*4+q] = s[q]; scrQ[wave][quad*4+q] = sq[q]; }
    }
    __syncthreads();
    #pragma unroll
    for (int q = 0; q < 4; ++q){
      const int rq = t0 + r0 + quad*4 + q;
      const float fs = s[q] + scrS[wave^2][quad*4+q];
      const float fq = sq[q] + scrQ[wave^2][quad*4+q];
      const float mean = fs*(1.f/D);
      const float rstd = rsqrtf(fq*(1.f/D) - mean*mean + 1e-5f);
      #pragma unroll
      for (int g = 0; g < 4; ++g)
        out[(size_t)rq*128 + c0 + g*16 + l15] = (v[g][q] - mean)*rstd;
    }
  }
}

// ---------------- resh: bf16-A GEMM + bias + residual + LN --------------------
__global__ __launch_bounds__(256) void gemm32b(
    const u16* __restrict__ A, int lda, int K,
    const u16* __restrict__ BT, const float* __restrict__ bias,
    const float* __restrict__ res, float* __restrict__ out)
{
  const int tid = threadIdx.x;
  const int t0 = blockIdx.x * 32;
  __shared__ float scrS[4][16], scrQ[4][16];
  const int wave = tid >> 6, lane = tid & 63, quad = lane >> 4, l15 = lane & 15;
  const int r0 = (wave & 1)*16, c0 = (wave >> 1)*64;
  facc acc[4];
  #pragma unroll
  for (int g = 0; g < 4; ++g) acc[g] = (facc){0.f,0.f,0.f,0.f};
  const u16* arow = A + (size_t)(t0 + r0 + l15)*lda + quad*8;
  const u16* Bg[4];
  #pragma unroll
  for (int g = 0; g < 4; ++g)
    Bg[g] = BT + (size_t)(c0 + g*16 + l15)*K + quad*8;

  for (int k0 = 0; k0 < K; k0 += 32){
    bfrag af = *(const bfrag*)(arow + k0);
    #pragma unroll
    for (int g = 0; g < 4; ++g){
      bfrag bf = *(const bfrag*)(Bg[g] + k0);
      acc[g] = __builtin_amdgcn_mfma_f32_16x16x32_bf16(af, bf, acc[g], 0,0,0);
    }
  }

  float bv[4];
  #pragma unroll
  for (int g = 0; g < 4; ++g) bv[g] = bias[c0 + g*16 + l15];
  float v[4][4], s[4] = {0,0,0,0}, sq[4] = {0,0,0,0};
  #pragma unroll
  for (int g = 0; g < 4; ++g){
    const int c = c0 + g*16 + l15;
    #pragma unroll
    for (int q = 0; q < 4; ++q){
      const int rq = t0 + r0 + quad*4 + q;
      float xv = acc[g][q] + bv[g] + res[(size_t)rq*128 + c];
      v[g][q] = xv; s[q] += xv; sq[q] += xv*xv;
    }
  }
  #pragma unroll
  for (int m = 1; m < 16; m <<= 1){
    #pragma unroll
    for (int q = 0; q < 4; ++q){ s[q] += __shfl_xor(s[q], m, 64); sq[q] += __shfl_xor(sq[q], m, 64); }
  }
  if (l15 == 0){
    #pragma unroll
    for (int q = 0; q < 4; ++q){ scrS[wave][quad*4+q] = s[q]; scrQ[wave][quad*4+q] = sq[q]; }
  }
  __syncthreads();
  #pragma unroll
  for (int q = 0; q < 4; ++q){
    const int rq = t0 + r0 + quad*4 + q;
    const float fs = s[q] + scrS[wave^2][quad*4+q];
    const float fq = sq[q] + scrQ[wave^2][quad*4+q];
    const float mean = fs*(1.f/D);
    const float rstd = rsqrtf(fq*(1.f/D) - mean*mean + 1e-5f);
    #pragma unroll
    for (int g = 0; g < 4; ++g)
      out[(size_t)rq*128 + c0 + g*16 + l15] = (v[g][q] - mean)*rstd;
  }
}

// ---------------- Wh + fused s1/s2 --------------------------------------------
__global__ __launch_bounds__(256) void wh32(
    const float* __restrict__ hin, const u16* __restrict__ WT,
    const float* __restrict__ a, u16* __restrict__ WhT,
    float* __restrict__ s1, float* __restrict__ s2)
{
  const int tid = threadIdx.x;
  const int h  = blockIdx.x >> 7;
  const int t0 = (blockIdx.x & 127) * 32;
  const int b = t0 >> 9, j0 = t0 & (N-1);
  __shared__ float r1s[2][32], r2s[2][32];
  const int wave = tid >> 6, lane = tid & 63, quad = lane >> 4, l15 = lane & 15;
  const int r0 = (wave & 1)*16, c0 = (wave >> 1)*64;
  facc acc[4];
  #pragma unroll
  for (int g = 0; g < 4; ++g) acc[g] = (facc){0.f,0.f,0.f,0.f};
  const float* arow = hin + (size_t)(t0 + r0 + l15)*D + quad*8;
  const u16* Wb = WT + (size_t)h*D*D;
  const u16* Bg[4];
  #pragma unroll
  for (int g = 0; g < 4; ++g)
    Bg[g] = Wb + (size_t)(c0 + g*16 + l15)*D + quad*8;

  #pragma unroll
  for (int k0 = 0; k0 < D; k0 += 32){
    float4 a0 = *(const float4*)(arow + k0);
    float4 a1 = *(const float4*)(arow + k0 + 4);
    bfrag af = pack8(a0, a1);
    #pragma unroll
    for (int g = 0; g < 4; ++g){
      bfrag bf = *(const bfrag*)(Bg[g] + k0);
      acc[g] = __builtin_amdgcn_mfma_f32_16x16x32_bf16(af, bf, acc[g], 0,0,0);
    }
  }

  const float* ah = a + (size_t)h*2*D;
  const size_t obase = (size_t)(h*8 + b)*128;
  float p1[4] = {0,0,0,0}, p2[4] = {0,0,0,0};
  #pragma unroll
  for (int g = 0; g < 4; ++g){
    const int c = c0 + g*16 + l15;
    const float a1v = ah[c], a2v = ah[D + c];
    ushort4 wv;
    wv.x = f2bf(acc[g][0]); wv.y = f2bf(acc[g][1]);
    wv.z = f2bf(acc[g][2]); wv.w = f2bf(acc[g][3]);
    *(ushort4*)&WhT[(obase + c)*N + j0 + r0 + quad*4] = wv;
    #pragma unroll
    for (int q = 0; q < 4; ++q){
      p1[q] = fmaf(acc[g][q], a1v, p1[q]);
      p2[q] = fmaf(acc[g][q], a2v, p2[q]);
    }
  }
  #pragma unroll
  for (int m = 1; m < 16; m <<= 1){
    #pragma unroll
    for (int q = 0; q < 4; ++q){ p1[q] += __shfl_xor(p1[q], m, 64); p2[q] += __shfl_xor(p2[q], m, 64); }
  }
  if (l15 == 0){
    #pragma unroll
    for (int q = 0; q < 4; ++q){
      r1s[wave>>1][r0 + quad*4 + q] = p1[q];
      r2s[wave>>1][r0 + quad*4 + q] = p2[q];
    }
  }
  __syncthreads();
  if (tid < 32){
    s1[(size_t)h*TOK + t0 + tid] = r1s[0][tid] + r1s[1][tid];
    s2[(size_t)h*TOK + t0 + tid] = r2s[0][tid] + r2s[1][tid];
  }
}

// ---------------- fused score+softmax+PV (unnormalized exp, in-register A) ----
template<int MODE, int OBF>
__global__ __launch_bounds__(256) void pv32(
    const float* __restrict__ s1, const float* __restrict__ s2,
    const int* __restrict__ mask, const u16* __restrict__ WhT,
    void* __restrict__ out_, int ldo, int hcs)
{
  const int tid = threadIdx.x;
  const int h  = blockIdx.x >> 7;
  const int t0 = (blockIdx.x & 127) * 32;
  const int b = t0 >> 9, i0 = t0 & (N-1);
  __shared__ float s2s[N];
  s2s[tid]     = s2[(size_t)h*TOK + b*N + tid];
  s2s[tid+256] = s2[(size_t)h*TOK + b*N + tid + 256];
  __syncthreads();

  const int wave = tid >> 6, lane = tid & 63, quad = lane >> 4, l15 = lane & 15;
  const int r0 = (wave & 1)*16, c0 = (wave >> 1)*64;
  facc acc[4];
  #pragma unroll
  for (int g = 0; g < 4; ++g) acc[g] = (facc){0.f,0.f,0.f,0.f};

  const float s1v = s1[(size_t)h*TOK + t0 + r0 + l15];
  const int* mrow = mask + ((size_t)b*N + i0 + r0 + l15)*N + quad*8;
  const u16* Bb = WhT + (size_t)(h*8 + b)*128*N;
  const u16* Bg[4];
  #pragma unroll
  for (int g = 0; g < 4; ++g)
    Bg[g] = Bb + (size_t)(c0 + g*16 + l15)*N + quad*8;
  float psum = 0.f;

  for (int k0 = 0; k0 < N; k0 += 32){
    const int jb = k0 + quad*8;
    int4 ma = *(const int4*)(mrow + k0);
    int4 mb = *(const int4*)(mrow + k0 + 4);
    float4 sa = *(const float4*)&s2s[jb];
    float4 sb = *(const float4*)&s2s[jb+4];
    int   mm[8] = {ma.x,ma.y,ma.z,ma.w,mb.x,mb.y,mb.z,mb.w};
    float ss[8] = {sa.x,sa.y,sa.z,sa.w,sb.x,sb.y,sb.z,sb.w};
    float v[8];
    #pragma unroll
    for (int i = 0; i < 8; ++i){
      float e = lrelu(s1v * ss[i]);
      float ex = (mm[i] > 0) ? __expf(e) : 0.f;
      v[i] = ex; psum += ex;
    }
    union { uint4 u; bfrag bfr; } cv;
    cv.u = (uint4){ pk2(v[0],v[1]), pk2(v[2],v[3]), pk2(v[4],v[5]), pk2(v[6],v[7]) };
    bfrag af = cv.bfr;
    #pragma unroll
    for (int g = 0; g < 4; ++g){
      bfrag bf = *(const bfrag*)(Bg[g] + k0);
      acc[g] = __builtin_amdgcn_mfma_f32_16x16x32_bf16(af, bf, acc[g], 0,0,0);
    }
  }

  // full row sum for row r0+l15: combine the 4 quads
  psum += __shfl_xor(psum, 16, 64);
  psum += __shfl_xor(psum, 32, 64);

  #pragma unroll
  for (int q = 0; q < 4; ++q){
    const int rr = quad*4 + q;                  // wave-local C row
    const float sv = __shfl(psum, rr, 64);      // lane rr holds row r0+rr sum
    const float inv = sv > 0.f ? 1.f/sv : 0.f;
    const int rq = t0 + r0 + rr;
    #pragma unroll
    for (int g = 0; g < 4; ++g){
      float xv = acc[g][q] * inv;
      xv = (MODE == 0) ? (xv > 0.f ? xv : expm1f(xv)) : lrelu(xv);
      const size_t idx = (size_t)rq*ldo + h*hcs + c0 + g*16 + l15;
      if (OBF) ((u16*)out_)[idx] = f2bf(xv);
      else     ((float*)out_)[idx] = xv;
    }
  }
}

// ---------------- mean over n + projection -----------------------------------
__global__ void final_kernel(const float* __restrict__ hF, const float* __restrict__ hT,
                             const float* __restrict__ pW, const float* __restrict__ pb,
                             float* __restrict__ out)
{
  const int b = blockIdx.x, c = threadIdx.x;
  __shared__ float scr[4];
  const float* src = (c < D) ? (hF + (size_t)b*N*D + c) : (hT + (size_t)b*N*D + (c - D));
  float s = 0.f;
  for (int n = 0; n < N; ++n) s += src[(size_t)n*D];
  s *= (1.f/N);
  float p = s * pW[c];
  #pragma unroll
  for (int m = 32; m; m >>= 1) p += __shfl_xor(p, m, 64);
  __syncthreads();
  if ((c & 63) == 0) scr[c >> 6] = p;
  __syncthreads();
  if (c == 0) out[b] = scr[0] + scr[1] + scr[2] + scr[3] + pb[0];
}

extern "C" void kernel_launch(void* const* d_in, const int* in_sizes, int n_in,
                              void* d_out, int out_size, void* d_ws, size_t ws_size,
                              hipStream_t stream)
{
  (void)in_sizes; (void)n_in; (void)out_size; (void)ws_size;
  const float* x    = (const float*)d_in[0];
  const int*   adj  = (const int*)d_in[1];
  const float* f1w1 = (const float*)d_in[3];
  const float* f1b1 = (const float*)d_in[4];
  const float* f1w2 = (const float*)d_in[5];
  const float* f1b2 = (const float*)d_in[6];
  const float* f2w1 = (const float*)d_in[7];
  const float* f2b1 = (const float*)d_in[8];
  const float* f2w2 = (const float*)d_in[9];
  const float* f2b2 = (const float*)d_in[10];
  const float* f3w1 = (const float*)d_in[11];
  const float* f3b1 = (const float*)d_in[12];
  const float* f3w2 = (const float*)d_in[13];
  const float* f3b2 = (const float*)d_in[14];
  const float* attW = (const float*)d_in[15];
  const float* attA = (const float*)d_in[16];
  const float* rshW = (const float*)d_in[17];
  const float* rshB = (const float*)d_in[18];
  const float* outW = (const float*)d_in[19];
  const float* outA = (const float*)d_in[20];
  const float* pW   = (const float*)d_in[21];
  const float* pb   = (const float*)d_in[22];

  char* w = (char*)d_ws;
  float* hA  = (float*)w; w += (size_t)TOK*128*4;
  float* hB  = (float*)w; w += (size_t)TOK*128*4;
  float* hF  = (float*)w; w += (size_t)TOK*128*4;
  float* hq  = (float*)w; w += (size_t)TOK*256*4;   // FEL 256-wide fp32 scratch
  u16*  hp2  = (u16*)w;  w += (size_t)TOK*512*2;    // pv bf16 output
  u16*  WhT  = (u16*)w;  w += (size_t)H*8*128*N*2;
  float* s1  = (float*)w; w += (size_t)H*TOK*4;
  float* s2  = (float*)w; w += (size_t)H*TOK*4;
  int* adjT  = (int*)w;  w += (size_t)B*N*N*4;
  u16* f1w1T = (u16*)w; w += 128*32*2;
  u16* f1w2T = (u16*)w; w += 128*128*2;
  u16* f2w1T = (u16*)w; w += 256*128*2;
  u16* f2w2T = (u16*)w; w += 128*256*2;
  u16* f3w1T = (u16*)w; w += 256*128*2;
  u16* f3w2T = (u16*)w; w += 128*256*2;
  u16* attWT = (u16*)w; w += (size_t)24*128*128*2;
  u16* outWT = (u16*)w; w += (size_t)2*128*128*2;
  u16* rshWT = (u16*)w; w += (size_t)6*128*512*2;

  prep_kernel<<<512,256,0,stream>>>(adj, adjT,
      f1w1, f1w2, f2w1, f2w2, f3w1, f3w2, attW, outW, rshW,
      f1w1T, f1w2T, f2w1T, f2w2T, f3w1T, f3w2T, attWT, outWT, rshWT);

  // ---- FEL: 6 GEMM stages ----
  gemm32<1,0><<<dim3(128,1),256,0,stream>>>(x,   32, 32,  f1w1T, f1b1, nullptr, hF, 128);
  gemm32<1,0><<<dim3(128,1),256,0,stream>>>(hF, 128, 128, f1w2T, f1b2, nullptr, hB, 128);
  gemm32<1,0><<<dim3(128,2),256,0,stream>>>(hB, 128, 128, f2w1T, f2b1, nullptr, hq, 256);
  gemm32<1,1><<<dim3(128,1),256,0,stream>>>(hq, 256, 256, f2w2T, f2b2, hB, hF, 128);
  gemm32<1,0><<<dim3(128,2),256,0,stream>>>(hF, 128, 128, f3w1T, f3b1, nullptr, hq, 256);
  gemm32<0,1><<<dim3(128,1),256,0,stream>>>(hq, 256, 256, f3w2T, f3b2, hF, hA, 128);

  // ---- forward attention blocks 0..2 ----
  float* cur = hA; float* nxt = hB;
  for (int i = 0; i < 3; ++i){
    wh32<<<H*128,256,0,stream>>>(cur, attWT + (size_t)i*H*D*D,
                                 attA + (size_t)i*H*2*D, WhT, s1, s2);
    pv32<0,1><<<H*128,256,0,stream>>>(s1, s2, adj, WhT, hp2, 512, 128);
    gemm32b<<<128,256,0,stream>>>(hp2, 512, 512,
        rshWT + (size_t)i*128*512, rshB + (size_t)i*D, cur, nxt);
    float* t_ = cur; cur = nxt; nxt = t_;
  }
  // forward output GAT (single head, lrelu) -> hF
  wh32<<<128,256,0,stream>>>(cur, outWT, outA, WhT, s1, s2);
  pv32<1,0><<<128,256,0,stream>>>(s1, s2, adj, WhT, hF, 128, 0);

  // ---- transposed attention blocks 3..5 ----
  cur = hF; nxt = hA;
  for (int i = 3; i < 6; ++i){
    wh32<<<H*128,256,0,stream>>>(cur, attWT + (size_t)i*H*D*D,
                                 attA + (size_t)i*H*2*D, WhT, s1, s2);
    pv32<0,1><<<H*128,256,0,stream>>>(s1, s2, adjT, WhT, hp2, 512, 128);
    gemm32b<<<128,256,0,stream>>>(hp2, 512, 512,
        rshWT + (size_t)i*128*512, rshB + (size_t)i*D, cur, nxt);
    cur = nxt; nxt = (cur == hA) ? hB : hA;
  }
  // transposed output GAT -> nxt (distinct from hF and cur)
  wh32<<<128,256,0,stream>>>(cur, outWT + 128*128, outA + 2*D, WhT, s1, s2);
  pv32<1,0><<<128,256,0,stream>>>(s1, s2, adjT, WhT, nxt, 128, 0);

  final_kernel<<<B,2*D,0,stream>>>(hF, nxt, pW, pb, (float*)d_out);
}

// Round 10
// 388.329 us; speedup vs baseline: 1.4031x; 1.4031x over previous
//
#include <hip/hip_runtime.h>
#include <math.h>

#define B 8
#define N 512
#define D 128
#define H 4
#define TOK (B*N)   // 4096

typedef __attribute__((ext_vector_type(8))) short bfrag;   // 8 bf16 (4 VGPRs)
typedef __attribute__((ext_vector_type(4))) float facc;    // 4 fp32 acc
typedef unsigned short u16;
typedef unsigned int u32;

__device__ __forceinline__ float lrelu(float x){ return x > 0.f ? x : 0.01f*x; }
__device__ __forceinline__ u16 f2bf(float f){
  u32 u = __float_as_uint(f);
  u += 0x7fffu + ((u >> 16) & 1u);     // RTNE
  return (u16)(u >> 16);
}
__device__ __forceinline__ u32 pk2(float a, float b){
  return (u32)f2bf(a) | ((u32)f2bf(b) << 16);
}

// LDS row stride for bf16 tiles: 72 u16 (16B-aligned, breaks pow2 banks)
#define LS 72

// ---------------- unified prep: adj transpose + all weight bf16-transposes ----
__global__ void prep_kernel(const int* __restrict__ adj, int* __restrict__ adjT,
    const float* s0, const float* s1_, const float* s2_, const float* s3,
    const float* s4, const float* s5, const float* s6, const float* s7,
    const float* s8,
    u16* d0, u16* d1, u16* d2, u16* d3, u16* d4, u16* d5, u16* d6, u16* d7, u16* d8)
{
  __shared__ float ftile[32][33];
  const int tid = threadIdx.x;
  const int tx = tid & 31, ty = tid >> 5;
  if (blockIdx.x < 128){
    int* it = (int*)&ftile[0][0];
    const int b = blockIdx.x >> 4, i0 = (blockIdx.x & 15)*32;
    for (int j0 = 0; j0 < N; j0 += 32){
      for (int r = ty; r < 32; r += 8)
        it[r*33 + tx] = adj[((size_t)b*N + i0 + r)*N + j0 + tx];
      __syncthreads();
      for (int r = ty; r < 32; r += 8)
        adjT[((size_t)b*N + j0 + r)*N + i0 + tx] = it[tx*33 + r];
      __syncthreads();
    }
  } else {
    const float* srcs[9] = {s0,s1_,s2_,s3,s4,s5,s6,s7,s8};
    u16* dsts[9] = {d0,d1,d2,d3,d4,d5,d6,d7,d8};
    const int Ks[9] = {32,128,128,256,128,256,128,128,512};
    const int Ns[9] = {128,128,256,128,256,128,128,128,128};
    const int zs[9] = {1,1,1,1,1,1,24,2,6};
    for (int job = (int)blockIdx.x - 128; job < 948; job += 384){
      int m = 0, base = 0;
      for (; m < 9; ++m){
        int cnt = (Ks[m]>>5)*(Ns[m]>>5)*zs[m];
        if (job < base + cnt) break;
        base += cnt;
      }
      const int rem = job - base;
      const int tn = Ns[m] >> 5;
      const int per = (Ks[m] >> 5)*tn;
      const int z = rem / per, t = rem % per;
      const int k0 = (t / tn)*32, n0 = (t % tn)*32;
      const float* src = srcs[m] + (size_t)z*Ks[m]*Ns[m];
      u16* dst = dsts[m] + (size_t)z*Ks[m]*Ns[m];
      __syncthreads();
      for (int r = ty; r < 32; r += 8)
        ftile[r][tx] = src[(size_t)(k0+r)*Ns[m] + n0 + tx];
      __syncthreads();
      for (int r = ty; r < 32; r += 8)
        dst[(size_t)(n0+r)*Ks[m] + k0 + tx] = f2bf(ftile[tx][r]);
    }
  }
}

// ---- shared MFMA helpers: 32x128 tile, 4 waves (r0=(w&1)*16, c0=(w>>1)*64) ---
__device__ __forceinline__ void stageB64(const u16* __restrict__ BTn, int ldb,
                                         int k0, u16* Bs, int tid){
  const int n = tid >> 1, part = tid & 1;
  const u16* wp = BTn + (size_t)n*ldb + k0 + part*32;
  uint4 w0 = *(const uint4*)wp,      w1 = *(const uint4*)(wp+8);
  uint4 w2 = *(const uint4*)(wp+16), w3 = *(const uint4*)(wp+24);
  *(uint4*)&Bs[n*LS + part*32]      = w0;
  *(uint4*)&Bs[n*LS + part*32 + 8]  = w1;
  *(uint4*)&Bs[n*LS + part*32 + 16] = w2;
  *(uint4*)&Bs[n*LS + part*32 + 24] = w3;
}
__device__ __forceinline__ void stageB32(const u16* __restrict__ BTn, int ldb,
                                         int k0, u16* Bs, int tid){
  const int n = tid >> 1, part = tid & 1;
  const u16* wp = BTn + (size_t)n*ldb + k0 + part*16;
  uint4 w0 = *(const uint4*)wp, w1 = *(const uint4*)(wp+8);
  *(uint4*)&Bs[n*LS + part*16]     = w0;
  *(uint4*)&Bs[n*LS + part*16 + 8] = w1;
}
__device__ __forceinline__ void mfma64(const u16* As, const u16* Bs,
                                       facc acc[4], int r0, int c0,
                                       int quad, int l15){
  #pragma unroll
  for (int kk = 0; kk < 2; ++kk){
    bfrag af = *(const bfrag*)&As[(r0 + l15)*LS + kk*32 + quad*8];
    #pragma unroll
    for (int g = 0; g < 4; ++g){
      bfrag bf = *(const bfrag*)&Bs[(c0 + g*16 + l15)*LS + kk*32 + quad*8];
      acc[g] = __builtin_amdgcn_mfma_f32_16x16x32_bf16(af, bf, acc[g], 0,0,0);
    }
  }
}
__device__ __forceinline__ void mfma32(const u16* As, const u16* Bs,
                                       facc acc[4], int r0, int c0,
                                       int quad, int l15){
  bfrag af = *(const bfrag*)&As[(r0 + l15)*LS + quad*8];
  #pragma unroll
  for (int g = 0; g < 4; ++g){
    bfrag bf = *(const bfrag*)&Bs[(c0 + g*16 + l15)*LS + quad*8];
    acc[g] = __builtin_amdgcn_mfma_f32_16x16x32_bf16(af, bf, acc[g], 0,0,0);
  }
}

// ---------------- generic 32x128-tile GEMM, fp32 A ----------------------------
// ACT: 0 none, 1 lrelu(x+bias). FIN 0: plain store; FIN 1: +res then LN.
template<int ACT, int FIN>
__global__ __launch_bounds__(256) void gemm32(
    const float* __restrict__ A, int lda, int K,
    const u16* __restrict__ BT, const float* __restrict__ bias,
    const float* __restrict__ res, float* __restrict__ out, int ldo)
{
  const int tid = threadIdx.x;
  const int t0 = blockIdx.x * 32;
  const int n0 = blockIdx.y * 128;
  __shared__ __align__(16) u16 As[32*LS];
  __shared__ __align__(16) u16 Bs[128*LS];
  __shared__ float scrS[4][16], scrQ[4][16];
  const int wave = tid >> 6, lane = tid & 63, quad = lane >> 4, l15 = lane & 15;
  const int r0 = (wave & 1)*16, c0 = (wave >> 1)*64;
  facc acc[4];
  #pragma unroll
  for (int g = 0; g < 4; ++g) acc[g] = (facc){0.f,0.f,0.f,0.f};
  const u16* BTn = BT + (size_t)n0*K;

  int k0 = 0;
  for (; k0 + 64 <= K; k0 += 64){
    { const int row = tid >> 3, ko = tid & 7;
      const float* ap = A + (size_t)(t0+row)*lda + k0 + ko*8;
      float4 a0 = *(const float4*)ap, a1 = *(const float4*)(ap+4);
      uint4 u = { pk2(a0.x,a0.y), pk2(a0.z,a0.w), pk2(a1.x,a1.y), pk2(a1.z,a1.w) };
      *(uint4*)&As[row*LS + ko*8] = u;
    }
    stageB64(BTn, K, k0, Bs, tid);
    __syncthreads();
    mfma64(As, Bs, acc, r0, c0, quad, l15);
    __syncthreads();
  }
  if (k0 < K){   // 32-wide remainder (K=32 case)
    { const int row = tid >> 3, ko = tid & 7;
      float4 a0 = *(const float4*)(A + (size_t)(t0+row)*lda + k0 + ko*4);
      uint2 u = { pk2(a0.x,a0.y), pk2(a0.z,a0.w) };
      *(uint2*)&As[row*LS + ko*4] = u;
    }
    stageB32(BTn, K, k0, Bs, tid);
    __syncthreads();
    mfma32(As, Bs, acc, r0, c0, quad, l15);
    __syncthreads();
  }

  float bv[4];
  #pragma unroll
  for (int g = 0; g < 4; ++g) bv[g] = bias[n0 + c0 + g*16 + l15];

  if (FIN == 0){
    #pragma unroll
    for (int g = 0; g < 4; ++g){
      const int c = n0 + c0 + g*16 + l15;
      #pragma unroll
      for (int q = 0; q < 4; ++q){
        const int rq = t0 + r0 + quad*4 + q;
        float xv = acc[g][q] + bv[g];
        if (ACT) xv = lrelu(xv);
        out[(size_t)rq*ldo + c] = xv;
      }
    }
  } else {
    float v[4][4], s[4] = {0,0,0,0}, sq[4] = {0,0,0,0};
    #pragma unroll
    for (int g = 0; g < 4; ++g){
      const int c = c0 + g*16 + l15;
      #pragma unroll
      for (int q = 0; q < 4; ++q){
        const int rq = t0 + r0 + quad*4 + q;
        float xv = acc[g][q] + bv[g];
        if (ACT) xv = lrelu(xv);
        xv += res[(size_t)rq*128 + c];
        v[g][q] = xv; s[q] += xv; sq[q] += xv*xv;
      }
    }
    #pragma unroll
    for (int m = 1; m < 16; m <<= 1){
      #pragma unroll
      for (int q = 0; q < 4; ++q){ s[q] += __shfl_xor(s[q], m, 64); sq[q] += __shfl_xor(sq[q], m, 64); }
    }
    if (l15 == 0){
      #pragma unroll
      for (int q = 0; q < 4; ++q){ scrS[wave][quad*4+q] = s[q]; scrQ[wave][quad*4+q] = sq[q]; }
    }
    __syncthreads();
    #pragma unroll
    for (int q = 0; q < 4; ++q){
      const int rq = t0 + r0 + quad*4 + q;
      const float fs = s[q] + scrS[wave^2][quad*4+q];
      const float fq = sq[q] + scrQ[wave^2][quad*4+q];
      const float mean = fs*(1.f/D);
      const float rstd = rsqrtf(fq*(1.f/D) - mean*mean + 1e-5f);
      #pragma unroll
      for (int g = 0; g < 4; ++g)
        out[(size_t)rq*128 + c0 + g*16 + l15] = (v[g][q] - mean)*rstd;
    }
  }
}

// ---------------- resh: bf16-A GEMM + bias + residual + LN --------------------
__global__ __launch_bounds__(256) void gemm32b(
    const u16* __restrict__ A, int lda, int K,
    const u16* __restrict__ BT, const float* __restrict__ bias,
    const float* __restrict__ res, float* __restrict__ out)
{
  const int tid = threadIdx.x;
  const int t0 = blockIdx.x * 32;
  __shared__ __align__(16) u16 As[32*LS];
  __shared__ __align__(16) u16 Bs[128*LS];
  __shared__ float scrS[4][16], scrQ[4][16];
  const int wave = tid >> 6, lane = tid & 63, quad = lane >> 4, l15 = lane & 15;
  const int r0 = (wave & 1)*16, c0 = (wave >> 1)*64;
  facc acc[4];
  #pragma unroll
  for (int g = 0; g < 4; ++g) acc[g] = (facc){0.f,0.f,0.f,0.f};

  for (int k0 = 0; k0 < K; k0 += 64){
    { const int row = tid >> 3, ko = tid & 7;
      uint4 u = *(const uint4*)(A + (size_t)(t0+row)*lda + k0 + ko*8);
      *(uint4*)&As[row*LS + ko*8] = u;
    }
    stageB64(BT, K, k0, Bs, tid);
    __syncthreads();
    mfma64(As, Bs, acc, r0, c0, quad, l15);
    __syncthreads();
  }

  float bv[4];
  #pragma unroll
  for (int g = 0; g < 4; ++g) bv[g] = bias[c0 + g*16 + l15];
  float v[4][4], s[4] = {0,0,0,0}, sq[4] = {0,0,0,0};
  #pragma unroll
  for (int g = 0; g < 4; ++g){
    const int c = c0 + g*16 + l15;
    #pragma unroll
    for (int q = 0; q < 4; ++q){
      const int rq = t0 + r0 + quad*4 + q;
      float xv = acc[g][q] + bv[g] + res[(size_t)rq*128 + c];
      v[g][q] = xv; s[q] += xv; sq[q] += xv*xv;
    }
  }
  #pragma unroll
  for (int m = 1; m < 16; m <<= 1){
    #pragma unroll
    for (int q = 0; q < 4; ++q){ s[q] += __shfl_xor(s[q], m, 64); sq[q] += __shfl_xor(sq[q], m, 64); }
  }
  if (l15 == 0){
    #pragma unroll
    for (int q = 0; q < 4; ++q){ scrS[wave][quad*4+q] = s[q]; scrQ[wave][quad*4+q] = sq[q]; }
  }
  __syncthreads();
  #pragma unroll
  for (int q = 0; q < 4; ++q){
    const int rq = t0 + r0 + quad*4 + q;
    const float fs = s[q] + scrS[wave^2][quad*4+q];
    const float fq = sq[q] + scrQ[wave^2][quad*4+q];
    const float mean = fs*(1.f/D);
    const float rstd = rsqrtf(fq*(1.f/D) - mean*mean + 1e-5f);
    #pragma unroll
    for (int g = 0; g < 4; ++g)
      out[(size_t)rq*128 + c0 + g*16 + l15] = (v[g][q] - mean)*rstd;
  }
}

// ---------------- Wh (32x128 tiles) + fused s1/s2 -----------------------------
__global__ __launch_bounds__(256) void wh32(
    const float* __restrict__ hin, const u16* __restrict__ WT,
    const float* __restrict__ a, u16* __restrict__ WhT,
    float* __restrict__ s1, float* __restrict__ s2)
{
  const int tid = threadIdx.x;
  const int h  = blockIdx.x >> 7;
  const int t0 = (blockIdx.x & 127) * 32;
  const int b = t0 >> 9, j0 = t0 & (N-1);
  __shared__ __align__(16) u16 As[32*LS];
  __shared__ __align__(16) u16 Bs[128*LS];
  __shared__ float r1s[2][32], r2s[2][32];
  const int wave = tid >> 6, lane = tid & 63, quad = lane >> 4, l15 = lane & 15;
  const int r0 = (wave & 1)*16, c0 = (wave >> 1)*64;
  facc acc[4];
  #pragma unroll
  for (int g = 0; g < 4; ++g) acc[g] = (facc){0.f,0.f,0.f,0.f};
  const u16* BTn = WT + (size_t)h*D*D;

  #pragma unroll
  for (int k0 = 0; k0 < D; k0 += 64){
    { const int row = tid >> 3, ko = tid & 7;
      const float* ap = hin + (size_t)(t0+row)*D + k0 + ko*8;
      float4 a0 = *(const float4*)ap, a1 = *(const float4*)(ap+4);
      uint4 u = { pk2(a0.x,a0.y), pk2(a0.z,a0.w), pk2(a1.x,a1.y), pk2(a1.z,a1.w) };
      *(uint4*)&As[row*LS + ko*8] = u;
    }
    stageB64(BTn, D, k0, Bs, tid);
    __syncthreads();
    mfma64(As, Bs, acc, r0, c0, quad, l15);
    __syncthreads();
  }

  const float* ah = a + (size_t)h*2*D;
  const size_t obase = (size_t)(h*8 + b)*128;
  float p1[4] = {0,0,0,0}, p2[4] = {0,0,0,0};
  #pragma unroll
  for (int g = 0; g < 4; ++g){
    const int c = c0 + g*16 + l15;
    const float a1v = ah[c], a2v = ah[D + c];
    ushort4 wv;
    wv.x = f2bf(acc[g][0]); wv.y = f2bf(acc[g][1]);
    wv.z = f2bf(acc[g][2]); wv.w = f2bf(acc[g][3]);
    *(ushort4*)&WhT[(obase + c)*N + j0 + r0 + quad*4] = wv;
    #pragma unroll
    for (int q = 0; q < 4; ++q){
      p1[q] = fmaf(acc[g][q], a1v, p1[q]);
      p2[q] = fmaf(acc[g][q], a2v, p2[q]);
    }
  }
  #pragma unroll
  for (int m = 1; m < 16; m <<= 1){
    #pragma unroll
    for (int q = 0; q < 4; ++q){ p1[q] += __shfl_xor(p1[q], m, 64); p2[q] += __shfl_xor(p2[q], m, 64); }
  }
  if (l15 == 0){
    #pragma unroll
    for (int q = 0; q < 4; ++q){
      r1s[wave>>1][r0 + quad*4 + q] = p1[q];
      r2s[wave>>1][r0 + quad*4 + q] = p2[q];
    }
  }
  __syncthreads();
  if (tid < 32){
    s1[(size_t)h*TOK + t0 + tid] = r1s[0][tid] + r1s[1][tid];
    s2[(size_t)h*TOK + t0 + tid] = r2s[0][tid] + r2s[1][tid];
  }
}

// ---------------- fused score+softmax+PV, unnormalized-exp --------------------
// MODE 0: elu, MODE 1: lrelu. OBF 1: bf16 out, OBF 0: fp32 out.
template<int MODE, int OBF>
__global__ __launch_bounds__(256) void pv32(
    const float* __restrict__ s1, const float* __restrict__ s2,
    const int* __restrict__ mask, const u16* __restrict__ WhT,
    void* __restrict__ out_, int ldo, int hcs)
{
  const int tid = threadIdx.x;
  const int h  = blockIdx.x >> 7;
  const int t0 = (blockIdx.x & 127) * 32;
  const int b = t0 >> 9, i0 = t0 & (N-1);
  __shared__ float s2s[N];
  __shared__ float s1s[32], sums[32];
  __shared__ __align__(16) u16 As[32*LS];
  __shared__ __align__(16) u16 Bs[128*LS];

  s2s[tid]     = s2[(size_t)h*TOK + b*N + tid];
  s2s[tid+256] = s2[(size_t)h*TOK + b*N + tid + 256];
  if (tid < 32) s1s[tid] = s1[(size_t)h*TOK + t0 + tid];
  __syncthreads();

  const u16* BTn = WhT + (size_t)(h*8 + b)*128*N;   // [o=128][j=512] bf16
  const int wave = tid >> 6, lane = tid & 63, quad = lane >> 4, l15 = lane & 15;
  const int r0 = (wave & 1)*16, c0 = (wave >> 1)*64;
  facc acc[4];
  #pragma unroll
  for (int g = 0; g < 4; ++g) acc[g] = (facc){0.f,0.f,0.f,0.f};

  const int lr = tid >> 3, lq = tid & 7;
  const float s1lr = s1s[lr];
  const int* mrow = mask + ((size_t)b*N + i0 + lr)*N;
  float psum = 0.f;

  for (int k0 = 0; k0 < N; k0 += 64){
    { const int jb = k0 + lq*8;
      int4 ma = *(const int4*)(mrow + jb);
      int4 mb = *(const int4*)(mrow + jb + 4);
      float4 sa = *(const float4*)&s2s[jb];
      float4 sb = *(const float4*)&s2s[jb+4];
      int   mm[8] = {ma.x,ma.y,ma.z,ma.w,mb.x,mb.y,mb.z,mb.w};
      float ss[8] = {sa.x,sa.y,sa.z,sa.w,sb.x,sb.y,sb.z,sb.w};
      float v[8];
      #pragma unroll
      for (int i = 0; i < 8; ++i){
        float e = lrelu(s1lr * ss[i]);
        float ex = (mm[i] > 0) ? __expf(e) : 0.f;
        v[i] = ex; psum += ex;
      }
      uint4 u = { pk2(v[0],v[1]), pk2(v[2],v[3]), pk2(v[4],v[5]), pk2(v[6],v[7]) };
      *(uint4*)&As[lr*LS + lq*8] = u;
    }
    stageB64(BTn, N, k0, Bs, tid);
    __syncthreads();
    mfma64(As, Bs, acc, r0, c0, quad, l15);
    __syncthreads();
  }

  #pragma unroll
  for (int m = 1; m < 8; m <<= 1) psum += __shfl_xor(psum, m, 64);
  if (lq == 0) sums[lr] = psum;
  __syncthreads();

  #pragma unroll
  for (int q = 0; q < 4; ++q){
    const int rr = r0 + quad*4 + q;
    const float sv = sums[rr];
    const float inv = sv > 0.f ? 1.f/sv : 0.f;
    const int rq = t0 + rr;
    #pragma unroll
    for (int g = 0; g < 4; ++g){
      float xv = acc[g][q] * inv;
      xv = (MODE == 0) ? (xv > 0.f ? xv : expm1f(xv)) : lrelu(xv);
      const size_t idx = (size_t)rq*ldo + h*hcs + c0 + g*16 + l15;
      if (OBF) ((u16*)out_)[idx] = f2bf(xv);
      else     ((float*)out_)[idx] = xv;
    }
  }
}

// ---------------- mean over n + projection -----------------------------------
__global__ void final_kernel(const float* __restrict__ hF, const float* __restrict__ hT,
                             const float* __restrict__ pW, const float* __restrict__ pb,
                             float* __restrict__ out)
{
  const int b = blockIdx.x, c = threadIdx.x;
  __shared__ float scr[4];
  const float* src = (c < D) ? (hF + (size_t)b*N*D + c) : (hT + (size_t)b*N*D + (c - D));
  float s = 0.f;
  for (int n = 0; n < N; ++n) s += src[(size_t)n*D];
  s *= (1.f/N);
  float p = s * pW[c];
  #pragma unroll
  for (int m = 32; m; m >>= 1) p += __shfl_xor(p, m, 64);
  __syncthreads();
  if ((c & 63) == 0) scr[c >> 6] = p;
  __syncthreads();
  if (c == 0) out[b] = scr[0] + scr[1] + scr[2] + scr[3] + pb[0];
}

extern "C" void kernel_launch(void* const* d_in, const int* in_sizes, int n_in,
                              void* d_out, int out_size, void* d_ws, size_t ws_size,
                              hipStream_t stream)
{
  (void)in_sizes; (void)n_in; (void)out_size; (void)ws_size;
  const float* x    = (const float*)d_in[0];
  const int*   adj  = (const int*)d_in[1];
  const float* f1w1 = (const float*)d_in[3];
  const float* f1b1 = (const float*)d_in[4];
  const float* f1w2 = (const float*)d_in[5];
  const float* f1b2 = (const float*)d_in[6];
  const float* f2w1 = (const float*)d_in[7];
  const float* f2b1 = (const float*)d_in[8];
  const float* f2w2 = (const float*)d_in[9];
  const float* f2b2 = (const float*)d_in[10];
  const float* f3w1 = (const float*)d_in[11];
  const float* f3b1 = (const float*)d_in[12];
  const float* f3w2 = (const float*)d_in[13];
  const float* f3b2 = (const float*)d_in[14];
  const float* attW = (const float*)d_in[15];
  const float* attA = (const float*)d_in[16];
  const float* rshW = (const float*)d_in[17];
  const float* rshB = (const float*)d_in[18];
  const float* outW = (const float*)d_in[19];
  const float* outA = (const float*)d_in[20];
  const float* pW   = (const float*)d_in[21];
  const float* pb   = (const float*)d_in[22];

  char* w = (char*)d_ws;
  float* hA  = (float*)w; w += (size_t)TOK*128*4;
  float* hB  = (float*)w; w += (size_t)TOK*128*4;
  float* hF  = (float*)w; w += (size_t)TOK*128*4;
  float* hq  = (float*)w; w += (size_t)TOK*256*4;   // FEL 256-wide fp32 scratch
  u16*  hp2  = (u16*)w;  w += (size_t)TOK*512*2;    // pv bf16 output
  u16*  WhT  = (u16*)w;  w += (size_t)H*8*128*N*2;
  float* s1  = (float*)w; w += (size_t)H*TOK*4;
  float* s2  = (float*)w; w += (size_t)H*TOK*4;
  int* adjT  = (int*)w;  w += (size_t)B*N*N*4;
  u16* f1w1T = (u16*)w; w += 128*32*2;
  u16* f1w2T = (u16*)w; w += 128*128*2;
  u16* f2w1T = (u16*)w; w += 256*128*2;
  u16* f2w2T = (u16*)w; w += 128*256*2;
  u16* f3w1T = (u16*)w; w += 256*128*2;
  u16* f3w2T = (u16*)w; w += 128*256*2;
  u16* attWT = (u16*)w; w += (size_t)24*128*128*2;
  u16* outWT = (u16*)w; w += (size_t)2*128*128*2;
  u16* rshWT = (u16*)w; w += (size_t)6*128*512*2;

  prep_kernel<<<512,256,0,stream>>>(adj, adjT,
      f1w1, f1w2, f2w1, f2w2, f3w1, f3w2, attW, outW, rshW,
      f1w1T, f1w2T, f2w1T, f2w2T, f3w1T, f3w2T, attWT, outWT, rshWT);

  // ---- FEL: 6 GEMM stages ----
  gemm32<1,0><<<dim3(128,1),256,0,stream>>>(x,   32, 32,  f1w1T, f1b1, nullptr, hF, 128);
  gemm32<1,0><<<dim3(128,1),256,0,stream>>>(hF, 128, 128, f1w2T, f1b2, nullptr, hB, 128);
  gemm32<1,0><<<dim3(128,2),256,0,stream>>>(hB, 128, 128, f2w1T, f2b1, nullptr, hq, 256);
  gemm32<1,1><<<dim3(128,1),256,0,stream>>>(hq, 256, 256, f2w2T, f2b2, hB, hF, 128);
  gemm32<1,0><<<dim3(128,2),256,0,stream>>>(hF, 128, 128, f3w1T, f3b1, nullptr, hq, 256);
  gemm32<0,1><<<dim3(128,1),256,0,stream>>>(hq, 256, 256, f3w2T, f3b2, hF, hA, 128);

  // ---- forward attention blocks 0..2 ----
  float* cur = hA; float* nxt = hB;
  for (int i = 0; i < 3; ++i){
    wh32<<<H*128,256,0,stream>>>(cur, attWT + (size_t)i*H*D*D,
                                 attA + (size_t)i*H*2*D, WhT, s1, s2);
    pv32<0,1><<<H*128,256,0,stream>>>(s1, s2, adj, WhT, hp2, 512, 128);
    gemm32b<<<128,256,0,stream>>>(hp2, 512, 512,
        rshWT + (size_t)i*128*512, rshB + (size_t)i*D, cur, nxt);
    float* t_ = cur; cur = nxt; nxt = t_;
  }
  // forward output GAT (single head, lrelu) -> hF
  wh32<<<128,256,0,stream>>>(cur, outWT, outA, WhT, s1, s2);
  pv32<1,0><<<128,256,0,stream>>>(s1, s2, adj, WhT, hF, 128, 0);

  // ---- transposed attention blocks 3..5 ----
  cur = hF; nxt = hA;
  for (int i = 3; i < 6; ++i){
    wh32<<<H*128,256,0,stream>>>(cur, attWT + (size_t)i*H*D*D,
                                 attA + (size_t)i*H*2*D, WhT, s1, s2);
    pv32<0,1><<<H*128,256,0,stream>>>(s1, s2, adjT, WhT, hp2, 512, 128);
    gemm32b<<<128,256,0,stream>>>(hp2, 512, 512,
        rshWT + (size_t)i*128*512, rshB + (size_t)i*D, cur, nxt);
    cur = nxt; nxt = (cur == hA) ? hB : hA;
  }
  // transposed output GAT -> nxt (distinct from hF and cur)
  wh32<<<128,256,0,stream>>>(cur, outWT + 128*128, outA + 2*D, WhT, s1, s2);
  pv32<1,0><<<128,256,0,stream>>>(s1, s2, adjT, WhT, nxt, 128, 0);

  final_kernel<<<B,2*D,0,stream>>>(hF, nxt, pW, pb, (float*)d_out);
}

// Round 11
// 380.638 us; speedup vs baseline: 1.4315x; 1.0202x over previous
//
#include <hip/hip_runtime.h>
#include <math.h>

#define B 8
#define N 512
#define D 128
#define H 4
#define TOK (B*N)   // 4096

typedef __attribute__((ext_vector_type(8))) short bfrag;   // 8 bf16 (4 VGPRs)
typedef __attribute__((ext_vector_type(4))) float facc;    // 4 fp32 acc
typedef unsigned short u16;
typedef unsigned int u32;

__device__ __forceinline__ float lrelu(float x){ return x > 0.f ? x : 0.01f*x; }
__device__ __forceinline__ u16 f2bf(float f){
  u32 u = __float_as_uint(f);
  u += 0x7fffu + ((u >> 16) & 1u);     // RTNE
  return (u16)(u >> 16);
}
__device__ __forceinline__ u32 pk2(float a, float b){
  return (u32)f2bf(a) | ((u32)f2bf(b) << 16);
}

// LDS row stride for bf16 tiles: 72 u16 (16B-aligned, breaks pow2 banks)
#define LS 72

// ---------------- unified prep: adj transpose + all weight bf16-transposes ----
__global__ void prep_kernel(const int* __restrict__ adj, int* __restrict__ adjT,
    const float* s0, const float* s1_, const float* s2_, const float* s3,
    const float* s4, const float* s5, const float* s6, const float* s7,
    const float* s8,
    u16* d0, u16* d1, u16* d2, u16* d3, u16* d4, u16* d5, u16* d6, u16* d7, u16* d8)
{
  __shared__ float ftile[32][33];
  const int tid = threadIdx.x;
  const int tx = tid & 31, ty = tid >> 5;
  if (blockIdx.x < 128){
    int* it = (int*)&ftile[0][0];
    const int b = blockIdx.x >> 4, i0 = (blockIdx.x & 15)*32;
    for (int j0 = 0; j0 < N; j0 += 32){
      for (int r = ty; r < 32; r += 8)
        it[r*33 + tx] = adj[((size_t)b*N + i0 + r)*N + j0 + tx];
      __syncthreads();
      for (int r = ty; r < 32; r += 8)
        adjT[((size_t)b*N + j0 + r)*N + i0 + tx] = it[tx*33 + r];
      __syncthreads();
    }
  } else {
    const float* srcs[9] = {s0,s1_,s2_,s3,s4,s5,s6,s7,s8};
    u16* dsts[9] = {d0,d1,d2,d3,d4,d5,d6,d7,d8};
    const int Ks[9] = {32,128,128,256,128,256,128,128,512};
    const int Ns[9] = {128,128,256,128,256,128,128,128,128};
    const int zs[9] = {1,1,1,1,1,1,24,2,6};
    for (int job = (int)blockIdx.x - 128; job < 948; job += 384){
      int m = 0, base = 0;
      for (; m < 9; ++m){
        int cnt = (Ks[m]>>5)*(Ns[m]>>5)*zs[m];
        if (job < base + cnt) break;
        base += cnt;
      }
      const int rem = job - base;
      const int tn = Ns[m] >> 5;
      const int per = (Ks[m] >> 5)*tn;
      const int z = rem / per, t = rem % per;
      const int k0 = (t / tn)*32, n0 = (t % tn)*32;
      const float* src = srcs[m] + (size_t)z*Ks[m]*Ns[m];
      u16* dst = dsts[m] + (size_t)z*Ks[m]*Ns[m];
      __syncthreads();
      for (int r = ty; r < 32; r += 8)
        ftile[r][tx] = src[(size_t)(k0+r)*Ns[m] + n0 + tx];
      __syncthreads();
      for (int r = ty; r < 32; r += 8)
        dst[(size_t)(n0+r)*Ks[m] + k0 + tx] = f2bf(ftile[tx][r]);
    }
  }
}

// ---- B staging helpers -------------------------------------------------------
__device__ __forceinline__ void stageB64(const u16* __restrict__ BTn, int ldb,
                                         int k0, u16* Bs, int tid){
  const int n = tid >> 1, part = tid & 1;
  const u16* wp = BTn + (size_t)n*ldb + k0 + part*32;
  uint4 w0 = *(const uint4*)wp,      w1 = *(const uint4*)(wp+8);
  uint4 w2 = *(const uint4*)(wp+16), w3 = *(const uint4*)(wp+24);
  *(uint4*)&Bs[n*LS + part*32]      = w0;
  *(uint4*)&Bs[n*LS + part*32 + 8]  = w1;
  *(uint4*)&Bs[n*LS + part*32 + 16] = w2;
  *(uint4*)&Bs[n*LS + part*32 + 24] = w3;
}
__device__ __forceinline__ void stageB32(const u16* __restrict__ BTn, int ldb,
                                         int k0, u16* Bs, int tid){
  const int n = tid >> 1, part = tid & 1;
  const u16* wp = BTn + (size_t)n*ldb + k0 + part*16;
  uint4 w0 = *(const uint4*)wp, w1 = *(const uint4*)(wp+8);
  *(uint4*)&Bs[n*LS + part*16]     = w0;
  *(uint4*)&Bs[n*LS + part*16 + 8] = w1;
}

// ---- 16x16x32 core, wave = 16 rows x 64 cols (gemm32 / wh32) -----------------
__device__ __forceinline__ void mfma64(const u16* As, const u16* Bs,
                                       facc acc[4], int r0, int c0,
                                       int quad, int l15){
  #pragma unroll
  for (int kk = 0; kk < 2; ++kk){
    bfrag af = *(const bfrag*)&As[(r0 + l15)*LS + kk*32 + quad*8];
    #pragma unroll
    for (int g = 0; g < 4; ++g){
      bfrag bf = *(const bfrag*)&Bs[(c0 + g*16 + l15)*LS + kk*32 + quad*8];
      acc[g] = __builtin_amdgcn_mfma_f32_16x16x32_bf16(af, bf, acc[g], 0,0,0);
    }
  }
}
__device__ __forceinline__ void mfma32(const u16* As, const u16* Bs,
                                       facc acc[4], int r0, int c0,
                                       int quad, int l15){
  bfrag af = *(const bfrag*)&As[(r0 + l15)*LS + quad*8];
  #pragma unroll
  for (int g = 0; g < 4; ++g){
    bfrag bf = *(const bfrag*)&Bs[(c0 + g*16 + l15)*LS + quad*8];
    acc[g] = __builtin_amdgcn_mfma_f32_16x16x32_bf16(af, bf, acc[g], 0,0,0);
  }
}

// ---- 16x16x32 core, wave = 32 rows x 32 cols (pv32 / gemm32b) ----------------
// B frag reused across both 16-row groups: 8 ds_read per chunk vs 10.
__device__ __forceinline__ void mfma64w(const u16* As, const u16* Bs,
                                        facc acc[2][2], int c0,
                                        int quad, int l15){
  #pragma unroll
  for (int kk = 0; kk < 2; ++kk){
    bfrag af0 = *(const bfrag*)&As[(l15)*LS      + kk*32 + quad*8];
    bfrag af1 = *(const bfrag*)&As[(16 + l15)*LS + kk*32 + quad*8];
    #pragma unroll
    for (int f = 0; f < 2; ++f){
      bfrag bf = *(const bfrag*)&Bs[(c0 + f*16 + l15)*LS + kk*32 + quad*8];
      acc[0][f] = __builtin_amdgcn_mfma_f32_16x16x32_bf16(af0, bf, acc[0][f], 0,0,0);
      acc[1][f] = __builtin_amdgcn_mfma_f32_16x16x32_bf16(af1, bf, acc[1][f], 0,0,0);
    }
  }
}

// ---------------- generic 32x128-tile GEMM, fp32 A (FEL; old core) ------------
template<int ACT, int FIN>
__global__ __launch_bounds__(256) void gemm32(
    const float* __restrict__ A, int lda, int K,
    const u16* __restrict__ BT, const float* __restrict__ bias,
    const float* __restrict__ res, float* __restrict__ out, int ldo)
{
  const int tid = threadIdx.x;
  const int t0 = blockIdx.x * 32;
  const int n0 = blockIdx.y * 128;
  __shared__ __align__(16) u16 As[32*LS];
  __shared__ __align__(16) u16 Bs[128*LS];
  __shared__ float scrS[4][16], scrQ[4][16];
  const int wave = tid >> 6, lane = tid & 63, quad = lane >> 4, l15 = lane & 15;
  const int r0 = (wave & 1)*16, c0 = (wave >> 1)*64;
  facc acc[4];
  #pragma unroll
  for (int g = 0; g < 4; ++g) acc[g] = (facc){0.f,0.f,0.f,0.f};
  const u16* BTn = BT + (size_t)n0*K;

  int k0 = 0;
  for (; k0 + 64 <= K; k0 += 64){
    { const int row = tid >> 3, ko = tid & 7;
      const float* ap = A + (size_t)(t0+row)*lda + k0 + ko*8;
      float4 a0 = *(const float4*)ap, a1 = *(const float4*)(ap+4);
      uint4 u = { pk2(a0.x,a0.y), pk2(a0.z,a0.w), pk2(a1.x,a1.y), pk2(a1.z,a1.w) };
      *(uint4*)&As[row*LS + ko*8] = u;
    }
    stageB64(BTn, K, k0, Bs, tid);
    __syncthreads();
    mfma64(As, Bs, acc, r0, c0, quad, l15);
    __syncthreads();
  }
  if (k0 < K){   // 32-wide remainder (K=32 case)
    { const int row = tid >> 3, ko = tid & 7;
      float4 a0 = *(const float4*)(A + (size_t)(t0+row)*lda + k0 + ko*4);
      uint2 u = { pk2(a0.x,a0.y), pk2(a0.z,a0.w) };
      *(uint2*)&As[row*LS + ko*4] = u;
    }
    stageB32(BTn, K, k0, Bs, tid);
    __syncthreads();
    mfma32(As, Bs, acc, r0, c0, quad, l15);
    __syncthreads();
  }

  float bv[4];
  #pragma unroll
  for (int g = 0; g < 4; ++g) bv[g] = bias[n0 + c0 + g*16 + l15];

  if (FIN == 0){
    #pragma unroll
    for (int g = 0; g < 4; ++g){
      const int c = n0 + c0 + g*16 + l15;
      #pragma unroll
      for (int q = 0; q < 4; ++q){
        const int rq = t0 + r0 + quad*4 + q;
        float xv = acc[g][q] + bv[g];
        if (ACT) xv = lrelu(xv);
        out[(size_t)rq*ldo + c] = xv;
      }
    }
  } else {
    float v[4][4], s[4] = {0,0,0,0}, sq[4] = {0,0,0,0};
    #pragma unroll
    for (int g = 0; g < 4; ++g){
      const int c = c0 + g*16 + l15;
      #pragma unroll
      for (int q = 0; q < 4; ++q){
        const int rq = t0 + r0 + quad*4 + q;
        float xv = acc[g][q] + bv[g];
        if (ACT) xv = lrelu(xv);
        xv += res[(size_t)rq*128 + c];
        v[g][q] = xv; s[q] += xv; sq[q] += xv*xv;
      }
    }
    #pragma unroll
    for (int m = 1; m < 16; m <<= 1){
      #pragma unroll
      for (int q = 0; q < 4; ++q){ s[q] += __shfl_xor(s[q], m, 64); sq[q] += __shfl_xor(sq[q], m, 64); }
    }
    if (l15 == 0){
      #pragma unroll
      for (int q = 0; q < 4; ++q){ scrS[wave][quad*4+q] = s[q]; scrQ[wave][quad*4+q] = sq[q]; }
    }
    __syncthreads();
    #pragma unroll
    for (int q = 0; q < 4; ++q){
      const int rq = t0 + r0 + quad*4 + q;
      const float fs = s[q] + scrS[wave^2][quad*4+q];
      const float fq = sq[q] + scrQ[wave^2][quad*4+q];
      const float mean = fs*(1.f/D);
      const float rstd = rsqrtf(fq*(1.f/D) - mean*mean + 1e-5f);
      #pragma unroll
      for (int g = 0; g < 4; ++g)
        out[(size_t)rq*128 + c0 + g*16 + l15] = (v[g][q] - mean)*rstd;
    }
  }
}

// ---------------- resh: bf16-A GEMM + bias + residual + LN (32x32 wave core) --
__global__ __launch_bounds__(256) void gemm32b(
    const u16* __restrict__ A, int lda, int K,
    const u16* __restrict__ BT, const float* __restrict__ bias,
    const float* __restrict__ res, float* __restrict__ out)
{
  const int tid = threadIdx.x;
  const int t0 = blockIdx.x * 32;
  __shared__ __align__(16) u16 As[32*LS];
  __shared__ __align__(16) u16 Bs[128*LS];
  __shared__ float scrS[4][32], scrQ[4][32];
  const int wave = tid >> 6, lane = tid & 63, quad = lane >> 4, l15 = lane & 15;
  const int c0 = wave*32;
  facc acc[2][2];
  #pragma unroll
  for (int rg = 0; rg < 2; ++rg)
    #pragma unroll
    for (int f = 0; f < 2; ++f) acc[rg][f] = (facc){0.f,0.f,0.f,0.f};

  for (int k0 = 0; k0 < K; k0 += 64){
    { const int row = tid >> 3, ko = tid & 7;
      uint4 u = *(const uint4*)(A + (size_t)(t0+row)*lda + k0 + ko*8);
      *(uint4*)&As[row*LS + ko*8] = u;
    }
    stageB64(BT, K, k0, Bs, tid);
    __syncthreads();
    mfma64w(As, Bs, acc, c0, quad, l15);
    __syncthreads();
  }

  float bv[2];
  #pragma unroll
  for (int f = 0; f < 2; ++f) bv[f] = bias[c0 + f*16 + l15];
  float v[2][2][4], s[2][4], sq[2][4];
  #pragma unroll
  for (int rg = 0; rg < 2; ++rg)
    #pragma unroll
    for (int q = 0; q < 4; ++q){ s[rg][q] = 0.f; sq[rg][q] = 0.f; }
  #pragma unroll
  for (int rg = 0; rg < 2; ++rg){
    #pragma unroll
    for (int f = 0; f < 2; ++f){
      const int c = c0 + f*16 + l15;
      #pragma unroll
      for (int q = 0; q < 4; ++q){
        const int rq = t0 + rg*16 + quad*4 + q;
        float xv = acc[rg][f][q] + bv[f] + res[(size_t)rq*128 + c];
        v[rg][f][q] = xv; s[rg][q] += xv; sq[rg][q] += xv*xv;
      }
    }
  }
  #pragma unroll
  for (int m = 1; m < 16; m <<= 1){
    #pragma unroll
    for (int rg = 0; rg < 2; ++rg)
      #pragma unroll
      for (int q = 0; q < 4; ++q){ s[rg][q] += __shfl_xor(s[rg][q], m, 64); sq[rg][q] += __shfl_xor(sq[rg][q], m, 64); }
  }
  if (l15 == 0){
    #pragma unroll
    for (int rg = 0; rg < 2; ++rg)
      #pragma unroll
      for (int q = 0; q < 4; ++q){
        scrS[wave][rg*16 + quad*4 + q] = s[rg][q];
        scrQ[wave][rg*16 + quad*4 + q] = sq[rg][q];
      }
  }
  __syncthreads();
  #pragma unroll
  for (int rg = 0; rg < 2; ++rg){
    #pragma unroll
    for (int q = 0; q < 4; ++q){
      const int row = rg*16 + quad*4 + q;
      const float fs = scrS[0][row] + scrS[1][row] + scrS[2][row] + scrS[3][row];
      const float fq = scrQ[0][row] + scrQ[1][row] + scrQ[2][row] + scrQ[3][row];
      const float mean = fs*(1.f/D);
      const float rstd = rsqrtf(fq*(1.f/D) - mean*mean + 1e-5f);
      #pragma unroll
      for (int f = 0; f < 2; ++f)
        out[(size_t)(t0+row)*128 + c0 + f*16 + l15] = (v[rg][f][q] - mean)*rstd;
    }
  }
}

// ---------------- Wh (32x128 tiles; old core) + fused s1/s2 -------------------
__global__ __launch_bounds__(256) void wh32(
    const float* __restrict__ hin, const u16* __restrict__ WT,
    const float* __restrict__ a, u16* __restrict__ WhT,
    float* __restrict__ s1, float* __restrict__ s2)
{
  const int tid = threadIdx.x;
  const int h  = blockIdx.x >> 7;
  const int t0 = (blockIdx.x & 127) * 32;
  const int b = t0 >> 9, j0 = t0 & (N-1);
  __shared__ __align__(16) u16 As[32*LS];
  __shared__ __align__(16) u16 Bs[128*LS];
  __shared__ float r1s[2][32], r2s[2][32];
  const int wave = tid >> 6, lane = tid & 63, quad = lane >> 4, l15 = lane & 15;
  const int r0 = (wave & 1)*16, c0 = (wave >> 1)*64;
  facc acc[4];
  #pragma unroll
  for (int g = 0; g < 4; ++g) acc[g] = (facc){0.f,0.f,0.f,0.f};
  const u16* BTn = WT + (size_t)h*D*D;

  #pragma unroll
  for (int k0 = 0; k0 < D; k0 += 64){
    { const int row = tid >> 3, ko = tid & 7;
      const float* ap = hin + (size_t)(t0+row)*D + k0 + ko*8;
      float4 a0 = *(const float4*)ap, a1 = *(const float4*)(ap+4);
      uint4 u = { pk2(a0.x,a0.y), pk2(a0.z,a0.w), pk2(a1.x,a1.y), pk2(a1.z,a1.w) };
      *(uint4*)&As[row*LS + ko*8] = u;
    }
    stageB64(BTn, D, k0, Bs, tid);
    __syncthreads();
    mfma64(As, Bs, acc, r0, c0, quad, l15);
    __syncthreads();
  }

  const float* ah = a + (size_t)h*2*D;
  const size_t obase = (size_t)(h*8 + b)*128;
  float p1[4] = {0,0,0,0}, p2[4] = {0,0,0,0};
  #pragma unroll
  for (int g = 0; g < 4; ++g){
    const int c = c0 + g*16 + l15;
    const float a1v = ah[c], a2v = ah[D + c];
    ushort4 wv;
    wv.x = f2bf(acc[g][0]); wv.y = f2bf(acc[g][1]);
    wv.z = f2bf(acc[g][2]); wv.w = f2bf(acc[g][3]);
    *(ushort4*)&WhT[(obase + c)*N + j0 + r0 + quad*4] = wv;
    #pragma unroll
    for (int q = 0; q < 4; ++q){
      p1[q] = fmaf(acc[g][q], a1v, p1[q]);
      p2[q] = fmaf(acc[g][q], a2v, p2[q]);
    }
  }
  #pragma unroll
  for (int m = 1; m < 16; m <<= 1){
    #pragma unroll
    for (int q = 0; q < 4; ++q){ p1[q] += __shfl_xor(p1[q], m, 64); p2[q] += __shfl_xor(p2[q], m, 64); }
  }
  if (l15 == 0){
    #pragma unroll
    for (int q = 0; q < 4; ++q){
      r1s[wave>>1][r0 + quad*4 + q] = p1[q];
      r2s[wave>>1][r0 + quad*4 + q] = p2[q];
    }
  }
  __syncthreads();
  if (tid < 32){
    s1[(size_t)h*TOK + t0 + tid] = r1s[0][tid] + r1s[1][tid];
    s2[(size_t)h*TOK + t0 + tid] = r2s[0][tid] + r2s[1][tid];
  }
}

// ---------------- fused score+softmax+PV (32x32 wave core, unnorm exp) --------
// MODE 0: elu, MODE 1: lrelu. OBF 1: bf16 out, OBF 0: fp32 out.
template<int MODE, int OBF>
__global__ __launch_bounds__(256) void pv32(
    const float* __restrict__ s1, const float* __restrict__ s2,
    const int* __restrict__ mask, const u16* __restrict__ WhT,
    void* __restrict__ out_, int ldo, int hcs)
{
  const int tid = threadIdx.x;
  const int h  = blockIdx.x >> 7;
  const int t0 = (blockIdx.x & 127) * 32;
  const int b = t0 >> 9, i0 = t0 & (N-1);
  __shared__ float s2s[N];
  __shared__ float s1s[32], sums[32];
  __shared__ __align__(16) u16 As[32*LS];
  __shared__ __align__(16) u16 Bs[128*LS];

  s2s[tid]     = s2[(size_t)h*TOK + b*N + tid];
  s2s[tid+256] = s2[(size_t)h*TOK + b*N + tid + 256];
  if (tid < 32) s1s[tid] = s1[(size_t)h*TOK + t0 + tid];
  __syncthreads();

  const u16* BTn = WhT + (size_t)(h*8 + b)*128*N;   // [o=128][j=512] bf16
  const int wave = tid >> 6, lane = tid & 63, quad = lane >> 4, l15 = lane & 15;
  const int c0 = wave*32;
  facc acc[2][2];
  #pragma unroll
  for (int rg = 0; rg < 2; ++rg)
    #pragma unroll
    for (int f = 0; f < 2; ++f) acc[rg][f] = (facc){0.f,0.f,0.f,0.f};

  const int lr = tid >> 3, lq = tid & 7;
  const float s1lr = s1s[lr];
  const int* mrow = mask + ((size_t)b*N + i0 + lr)*N;
  float psum = 0.f;

  for (int k0 = 0; k0 < N; k0 += 64){
    { const int jb = k0 + lq*8;
      int4 ma = *(const int4*)(mrow + jb);
      int4 mb = *(const int4*)(mrow + jb + 4);
      float4 sa = *(const float4*)&s2s[jb];
      float4 sb = *(const float4*)&s2s[jb+4];
      int   mm[8] = {ma.x,ma.y,ma.z,ma.w,mb.x,mb.y,mb.z,mb.w};
      float ss[8] = {sa.x,sa.y,sa.z,sa.w,sb.x,sb.y,sb.z,sb.w};
      float v[8];
      #pragma unroll
      for (int i = 0; i < 8; ++i){
        float e = lrelu(s1lr * ss[i]);
        float ex = (mm[i] > 0) ? __expf(e) : 0.f;
        v[i] = ex; psum += ex;
      }
      uint4 u = { pk2(v[0],v[1]), pk2(v[2],v[3]), pk2(v[4],v[5]), pk2(v[6],v[7]) };
      *(uint4*)&As[lr*LS + lq*8] = u;
    }
    stageB64(BTn, N, k0, Bs, tid);
    __syncthreads();
    mfma64w(As, Bs, acc, c0, quad, l15);
    __syncthreads();
  }

  #pragma unroll
  for (int m = 1; m < 8; m <<= 1) psum += __shfl_xor(psum, m, 64);
  if (lq == 0) sums[lr] = psum;
  __syncthreads();

  #pragma unroll
  for (int rg = 0; rg < 2; ++rg){
    #pragma unroll
    for (int q = 0; q < 4; ++q){
      const int row = rg*16 + quad*4 + q;
      const float sv = sums[row];
      const float inv = sv > 0.f ? 1.f/sv : 0.f;
      const int rq = t0 + row;
      #pragma unroll
      for (int f = 0; f < 2; ++f){
        float xv = acc[rg][f][q] * inv;
        xv = (MODE == 0) ? (xv > 0.f ? xv : __expf(xv) - 1.f) : lrelu(xv);
        const size_t idx = (size_t)rq*ldo + h*hcs + c0 + f*16 + l15;
        if (OBF) ((u16*)out_)[idx] = f2bf(xv);
        else     ((float*)out_)[idx] = xv;
      }
    }
  }
}

// ---------------- mean over n + projection -----------------------------------
__global__ void final_kernel(const float* __restrict__ hF, const float* __restrict__ hT,
                             const float* __restrict__ pW, const float* __restrict__ pb,
                             float* __restrict__ out)
{
  const int b = blockIdx.x, c = threadIdx.x;
  __shared__ float scr[4];
  const float* src = (c < D) ? (hF + (size_t)b*N*D + c) : (hT + (size_t)b*N*D + (c - D));
  float s = 0.f;
  for (int n = 0; n < N; ++n) s += src[(size_t)n*D];
  s *= (1.f/N);
  float p = s * pW[c];
  #pragma unroll
  for (int m = 32; m; m >>= 1) p += __shfl_xor(p, m, 64);
  __syncthreads();
  if ((c & 63) == 0) scr[c >> 6] = p;
  __syncthreads();
  if (c == 0) out[b] = scr[0] + scr[1] + scr[2] + scr[3] + pb[0];
}

extern "C" void kernel_launch(void* const* d_in, const int* in_sizes, int n_in,
                              void* d_out, int out_size, void* d_ws, size_t ws_size,
                              hipStream_t stream)
{
  (void)in_sizes; (void)n_in; (void)out_size; (void)ws_size;
  const float* x    = (const float*)d_in[0];
  const int*   adj  = (const int*)d_in[1];
  const float* f1w1 = (const float*)d_in[3];
  const float* f1b1 = (const float*)d_in[4];
  const float* f1w2 = (const float*)d_in[5];
  const float* f1b2 = (const float*)d_in[6];
  const float* f2w1 = (const float*)d_in[7];
  const float* f2b1 = (const float*)d_in[8];
  const float* f2w2 = (const float*)d_in[9];
  const float* f2b2 = (const float*)d_in[10];
  const float* f3w1 = (const float*)d_in[11];
  const float* f3b1 = (const float*)d_in[12];
  const float* f3w2 = (const float*)d_in[13];
  const float* f3b2 = (const float*)d_in[14];
  const float* attW = (const float*)d_in[15];
  const float* attA = (const float*)d_in[16];
  const float* rshW = (const float*)d_in[17];
  const float* rshB = (const float*)d_in[18];
  const float* outW = (const float*)d_in[19];
  const float* outA = (const float*)d_in[20];
  const float* pW   = (const float*)d_in[21];
  const float* pb   = (const float*)d_in[22];

  char* w = (char*)d_ws;
  float* hA  = (float*)w; w += (size_t)TOK*128*4;
  float* hB  = (float*)w; w += (size_t)TOK*128*4;
  float* hF  = (float*)w; w += (size_t)TOK*128*4;
  float* hq  = (float*)w; w += (size_t)TOK*256*4;   // FEL 256-wide fp32 scratch
  u16*  hp2  = (u16*)w;  w += (size_t)TOK*512*2;    // pv bf16 output
  u16*  WhT  = (u16*)w;  w += (size_t)H*8*128*N*2;
  float* s1  = (float*)w; w += (size_t)H*TOK*4;
  float* s2  = (float*)w; w += (size_t)H*TOK*4;
  int* adjT  = (int*)w;  w += (size_t)B*N*N*4;
  u16* f1w1T = (u16*)w; w += 128*32*2;
  u16* f1w2T = (u16*)w; w += 128*128*2;
  u16* f2w1T = (u16*)w; w += 256*128*2;
  u16* f2w2T = (u16*)w; w += 128*256*2;
  u16* f3w1T = (u16*)w; w += 256*128*2;
  u16* f3w2T = (u16*)w; w += 128*256*2;
  u16* attWT = (u16*)w; w += (size_t)24*128*128*2;
  u16* outWT = (u16*)w; w += (size_t)2*128*128*2;
  u16* rshWT = (u16*)w; w += (size_t)6*128*512*2;

  prep_kernel<<<512,256,0,stream>>>(adj, adjT,
      f1w1, f1w2, f2w1, f2w2, f3w1, f3w2, attW, outW, rshW,
      f1w1T, f1w2T, f2w1T, f2w2T, f3w1T, f3w2T, attWT, outWT, rshWT);

  // ---- FEL: 6 GEMM stages ----
  gemm32<1,0><<<dim3(128,1),256,0,stream>>>(x,   32, 32,  f1w1T, f1b1, nullptr, hF, 128);
  gemm32<1,0><<<dim3(128,1),256,0,stream>>>(hF, 128, 128, f1w2T, f1b2, nullptr, hB, 128);
  gemm32<1,0><<<dim3(128,2),256,0,stream>>>(hB, 128, 128, f2w1T, f2b1, nullptr, hq, 256);
  gemm32<1,1><<<dim3(128,1),256,0,stream>>>(hq, 256, 256, f2w2T, f2b2, hB, hF, 128);
  gemm32<1,0><<<dim3(128,2),256,0,stream>>>(hF, 128, 128, f3w1T, f3b1, nullptr, hq, 256);
  gemm32<0,1><<<dim3(128,1),256,0,stream>>>(hq, 256, 256, f3w2T, f3b2, hF, hA, 128);

  // ---- forward attention blocks 0..2 ----
  float* cur = hA; float* nxt = hB;
  for (int i = 0; i < 3; ++i){
    wh32<<<H*128,256,0,stream>>>(cur, attWT + (size_t)i*H*D*D,
                                 attA + (size_t)i*H*2*D, WhT, s1, s2);
    pv32<0,1><<<H*128,256,0,stream>>>(s1, s2, adj, WhT, hp2, 512, 128);
    gemm32b<<<128,256,0,stream>>>(hp2, 512, 512,
        rshWT + (size_t)i*128*512, rshB + (size_t)i*D, cur, nxt);
    float* t_ = cur; cur = nxt; nxt = t_;
  }
  // forward output GAT (single head, lrelu) -> hF
  wh32<<<128,256,0,stream>>>(cur, outWT, outA, WhT, s1, s2);
  pv32<1,0><<<128,256,0,stream>>>(s1, s2, adj, WhT, hF, 128, 0);

  // ---- transposed attention blocks 3..5 ----
  cur = hF; nxt = hA;
  for (int i = 3; i < 6; ++i){
    wh32<<<H*128,256,0,stream>>>(cur, attWT + (size_t)i*H*D*D,
                                 attA + (size_t)i*H*2*D, WhT, s1, s2);
    pv32<0,1><<<H*128,256,0,stream>>>(s1, s2, adjT, WhT, hp2, 512, 128);
    gemm32b<<<128,256,0,stream>>>(hp2, 512, 512,
        rshWT + (size_t)i*128*512, rshB + (size_t)i*D, cur, nxt);
    cur = nxt; nxt = (cur == hA) ? hB : hA;
  }
  // transposed output GAT -> nxt (distinct from hF and cur)
  wh32<<<128,256,0,stream>>>(cur, outWT + 128*128, outA + 2*D, WhT, s1, s2);
  pv32<1,0><<<128,256,0,stream>>>(s1, s2, adjT, WhT, nxt, 128, 0);

  final_kernel<<<B,2*D,0,stream>>>(hF, nxt, pW, pb, (float*)d_out);
}